// Round 2
// baseline (511.892 us; speedup 1.0000x reference)
//
#include <hip/hip_runtime.h>

// Problem constants (match reference)
#define NNODE 100000   // N_SRC == N_DST
#define EDG   500000
#define DD    128
#define FF    64
#define NBAS  2
#define NCLS  5

// Workspace layout, in ushort (bf16) units. Packed-B layout per GEMM:
// B'[g][n][j] = B[g*8+j][n], g = k/8, so a lane's 8 k-contiguous B elements
// for MFMA 16x16x32 are one 16B load at ((ks*4+quad)*128 + n)*8.
#define OFF_B1   0                       // K=64  : 8*128*8
#define OFF_B2   8192                    // K=128 : 16*128*8
#define OFF_B3   24576
#define OFF_BCR  40960
#define OFF_BCL  57344
#define OFF_P0   73728
#define OFF_P1   90112
#define OFF_HU   106496                  // [NNODE][128] bf16
#define OFF_HV   (106496 + NNODE * DD)
#define PREP_TOT 106496

typedef __attribute__((ext_vector_type(8))) short short8;
typedef __attribute__((ext_vector_type(4))) float f32x4;

__device__ __forceinline__ float bf2f(ushort u) {
  return __uint_as_float(((unsigned int)u) << 16);
}
__device__ __forceinline__ ushort f2bf(float f) {
  unsigned int u = __float_as_uint(f);
  u += 0x7FFF + ((u >> 16) & 1);   // round-to-nearest-even
  return (ushort)(u >> 16);
}

__device__ __forceinline__ void zacc(f32x4 a[4][2]) {
#pragma unroll
  for (int i = 0; i < 4; ++i)
#pragma unroll
    for (int j = 0; j < 2; ++j)
      a[i][j] = (f32x4){0.f, 0.f, 0.f, 0.f};
}

// Workgroup GEMM: C[64 rows][128 cols] += ACT[64][K] * B[K][128].
// 4 waves; wave w owns cols [w*32, w*32+32). A-frags from LDS (padded stride
// 136), B-frags straight from global (L2-hot, perfectly coalesced 16B/lane).
__device__ __forceinline__ void gemm_core(const ushort act[][136],
                                          const ushort* __restrict__ Bp,
                                          int ksteps, f32x4 acc[4][2],
                                          int w, int l15, int q) {
  for (int ks = 0; ks < ksteps; ++ks) {
    short8 bfrag[2], afrag[4];
#pragma unroll
    for (int c2 = 0; c2 < 2; ++c2) {
      int n = w * 32 + c2 * 16 + l15;
      bfrag[c2] = *(const short8*)(Bp + ((ks * 4 + q) * 128 + n) * 8);
    }
#pragma unroll
    for (int rt = 0; rt < 4; ++rt)
      afrag[rt] = *(const short8*)&act[rt * 16 + l15][ks * 32 + q * 8];
#pragma unroll
    for (int rt = 0; rt < 4; ++rt)
#pragma unroll
      for (int c2 = 0; c2 < 2; ++c2)
        acc[rt][c2] = __builtin_amdgcn_mfma_f32_16x16x32_bf16(
            afrag[rt], bfrag[c2], acc[rt][c2], 0, 0, 0);
  }
}

// Epilogue: C/D layout is col = lane&15, row = quad*4 + reg (guide-verified).
__device__ __forceinline__ void store_tiles(ushort dest[][136], f32x4 acc[4][2],
                                            const float* __restrict__ bias,
                                            int relu, int w, int l15, int q) {
#pragma unroll
  for (int rt = 0; rt < 4; ++rt)
#pragma unroll
    for (int c2 = 0; c2 < 2; ++c2) {
      int col = w * 32 + c2 * 16 + l15;
      float bv = bias ? bias[col] : 0.f;
#pragma unroll
      for (int r = 0; r < 4; ++r) {
        int row = rt * 16 + q * 4 + r;
        float v = acc[rt][c2][r] + bv;
        if (relu) v = fmaxf(v, 0.f);
        dest[row][col] = f2bf(v);
      }
    }
}

// ---------------- prep: pack all weights to bf16 fragment layout ----------
__global__ void __launch_bounds__(256) prep_kernel(
    const float* __restrict__ W1, const float* __restrict__ W2,
    const float* __restrict__ W3, const float* __restrict__ W_comb,
    const float* __restrict__ P, ushort* __restrict__ ws) {
  int idx = blockIdx.x * 256 + threadIdx.x;
  if (idx >= PREP_TOT) return;
  float val;
  if (idx < 8192) {                       // W1^T, K=64: B[k][n] = W1[n][k]
    int g = idx >> 10, n = (idx >> 3) & 127, j = idx & 7, k = g * 8 + j;
    val = W1[n * 64 + k];
  } else {
    int i2 = idx - 8192;
    int m = i2 >> 14, r = i2 & 16383;
    int g = r >> 10, n = (r >> 3) & 127, j = r & 7, k = g * 8 + j;
    switch (m) {
      case 0:  val = W2[n * 128 + k]; break;              // W2^T
      case 1:  val = W3[n * 128 + k]; break;              // W3^T
      case 2:  val = W_comb[n * 256 + 128 + k]; break;    // Wcr^T
      case 3:  val = W_comb[n * 256 + k]; break;          // Wcl^T
      case 4:  val = P[n * 128 + k]; break;               // P0: B[j][i]=P[0,i,j]
      default: val = P[16384 + n * 128 + k]; break;       // P1
    }
  }
  ws[idx] = f2bf(val);
}

// ---------------- node kernel: hu = h_src @ Wcl^T, hv = h_dst @ Wcl^T -----
__global__ void __launch_bounds__(256) node_kernel(
    const float* __restrict__ h_src, const float* __restrict__ h_dst,
    ushort* __restrict__ ws) {
  __shared__ ushort ACT[64][136];
  const int NT = (NNODE + 63) / 64;
  const int tid = threadIdx.x;
  const int w = tid >> 6, lane = tid & 63, l15 = lane & 15, q = lane >> 4;
  const int bb = blockIdx.x;
  const float* h = (bb < NT) ? h_src : h_dst;
  ushort* op = ws + ((bb < NT) ? OFF_HU : OFF_HV);
  const int tile = (bb < NT) ? bb : bb - NT;
  const int r0 = tile * 64;
  {
    const int r = tid >> 2, part = tid & 3;
    int row = r0 + r; if (row >= NNODE) row = NNODE - 1;
    const float4* src = (const float4*)(h + (long)row * DD) + part * 8;
    ushort* dst = &ACT[r][part * 32];
#pragma unroll
    for (int i = 0; i < 8; ++i) {
      float4 v = src[i];
      ushort4 hh; hh.x = f2bf(v.x); hh.y = f2bf(v.y);
      hh.z = f2bf(v.z); hh.w = f2bf(v.w);
      *(ushort4*)(dst + i * 4) = hh;
    }
  }
  __syncthreads();
  f32x4 acc[4][2];
  zacc(acc);
  gemm_core(ACT, ws + OFF_BCL, 4, acc, w, l15, q);
#pragma unroll
  for (int rt = 0; rt < 4; ++rt)
#pragma unroll
    for (int c2 = 0; c2 < 2; ++c2) {
      int col = w * 32 + c2 * 16 + l15;
#pragma unroll
      for (int r = 0; r < 4; ++r) {
        int row = r0 + rt * 16 + q * 4 + r;
        if (row < NNODE) op[(long)row * DD + col] = f2bf(acc[rt][c2][r]);
      }
    }
}

// ---------------- fused edge kernel ---------------------------------------
__global__ void __launch_bounds__(256) edge_kernel(
    const float* __restrict__ efeats, const int* __restrict__ u_idx,
    const int* __restrict__ v_idx, const float* __restrict__ b1,
    const float* __restrict__ b2, const float* __restrict__ b3,
    const float* __restrict__ W_cb, const ushort* __restrict__ ws,
    float* __restrict__ out) {
  __shared__ ushort ACT[64][136];   // activation ping buffer (X,e1,e2,e3,V,U)
  __shared__ ushort EC[64][136];    // ec = e3 @ Wcr^T
  __shared__ float OB[64][2];       // bilinear outputs per basis

  const int tid = threadIdx.x;
  const int w = tid >> 6, lane = tid & 63;
  const int l15 = lane & 15, q = lane >> 4;
  const long e0 = (long)blockIdx.x * 64;

  // stage X = bf16(efeats tile) [64][64]
  {
    const int r = tid >> 2, part = tid & 3;
    long row = e0 + r; if (row >= EDG) row = EDG - 1;
    const float4* src = (const float4*)(efeats + row * FF) + part * 4;
    ushort* dst = &ACT[r][part * 16];
#pragma unroll
    for (int i = 0; i < 4; ++i) {
      float4 v = src[i];
      ushort4 hh; hh.x = f2bf(v.x); hh.y = f2bf(v.y);
      hh.z = f2bf(v.z); hh.w = f2bf(v.w);
      *(ushort4*)(dst + i * 4) = hh;
    }
  }
  __syncthreads();

  f32x4 acc[4][2];
  // e1 = relu(X @ W1^T + b1), K=64
  zacc(acc); gemm_core(ACT, ws + OFF_B1, 2, acc, w, l15, q);
  __syncthreads(); store_tiles(ACT, acc, b1, 1, w, l15, q); __syncthreads();
  // e2 = relu(e1 @ W2^T + b2)
  zacc(acc); gemm_core(ACT, ws + OFF_B2, 4, acc, w, l15, q);
  __syncthreads(); store_tiles(ACT, acc, b2, 1, w, l15, q); __syncthreads();
  // e3 = e2 @ W3^T + b3   (no relu)
  zacc(acc); gemm_core(ACT, ws + OFF_B3, 4, acc, w, l15, q);
  __syncthreads(); store_tiles(ACT, acc, b3, 0, w, l15, q); __syncthreads();
  // ec = e3 @ Wcr^T
  zacc(acc); gemm_core(ACT, ws + OFF_BCR, 4, acc, w, l15, q);
  __syncthreads(); store_tiles(EC, acc, nullptr, 0, w, l15, q); __syncthreads();

  // V = hv[v_idx] + ec  -> ACT
  {
    const int r = tid >> 2, part = tid & 3;
    long row = e0 + r; if (row >= EDG) row = EDG - 1;
    const int vi = v_idx[row];
    const ushort* hp = ws + OFF_HV + (long)vi * DD + part * 32;
    const ushort* ep = &EC[r][part * 32];
    ushort* dst = &ACT[r][part * 32];
#pragma unroll
    for (int ch = 0; ch < 8; ++ch) {
      ushort4 a = *(const ushort4*)(hp + ch * 4);
      ushort4 b = *(const ushort4*)(ep + ch * 4);
      ushort4 o;
      o.x = f2bf(bf2f(a.x) + bf2f(b.x));
      o.y = f2bf(bf2f(a.y) + bf2f(b.y));
      o.z = f2bf(bf2f(a.z) + bf2f(b.z));
      o.w = f2bf(bf2f(a.w) + bf2f(b.w));
      *(ushort4*)(dst + ch * 4) = o;
    }
  }
  __syncthreads();

  // T_b = V @ P_b^T, kept in registers
  f32x4 tacc[2][4][2];
  zacc(tacc[0]); zacc(tacc[1]);
  gemm_core(ACT, ws + OFF_P0, 4, tacc[0], w, l15, q);
  gemm_core(ACT, ws + OFF_P1, 4, tacc[1], w, l15, q);
  __syncthreads();

  // U = hu[u_idx] + ec  -> ACT (V no longer needed); zero OB
  {
    const int r = tid >> 2, part = tid & 3;
    long row = e0 + r; if (row >= EDG) row = EDG - 1;
    const int ui = u_idx[row];
    const ushort* hp = ws + OFF_HU + (long)ui * DD + part * 32;
    const ushort* ep = &EC[r][part * 32];
    ushort* dst = &ACT[r][part * 32];
#pragma unroll
    for (int ch = 0; ch < 8; ++ch) {
      ushort4 a = *(const ushort4*)(hp + ch * 4);
      ushort4 b = *(const ushort4*)(ep + ch * 4);
      ushort4 o;
      o.x = f2bf(bf2f(a.x) + bf2f(b.x));
      o.y = f2bf(bf2f(a.y) + bf2f(b.y));
      o.z = f2bf(bf2f(a.z) + bf2f(b.z));
      o.w = f2bf(bf2f(a.w) + bf2f(b.w));
      *(ushort4*)(dst + ch * 4) = o;
    }
    if (tid < 128) OB[tid >> 1][tid & 1] = 0.f;
  }
  __syncthreads();

  // out_b[row] = sum_col U[row][col] * T_b[row][col]
#pragma unroll
  for (int b = 0; b < 2; ++b)
#pragma unroll
    for (int rt = 0; rt < 4; ++rt) {
      float p[4] = {0.f, 0.f, 0.f, 0.f};
#pragma unroll
      for (int c2 = 0; c2 < 2; ++c2) {
        int col = w * 32 + c2 * 16 + l15;
        int rbase = rt * 16 + q * 4;
#pragma unroll
        for (int r = 0; r < 4; ++r)
          p[r] += tacc[b][rt][c2][r] * bf2f(ACT[rbase + r][col]);
      }
#pragma unroll
      for (int m = 1; m < 16; m <<= 1) {
#pragma unroll
        for (int r = 0; r < 4; ++r) p[r] += __shfl_xor(p[r], m, 64);
      }
      if (l15 == 0) {
        int rbase = rt * 16 + q * 4;
#pragma unroll
        for (int r = 0; r < 4; ++r) atomicAdd(&OB[rbase + r][b], p[r]);
      }
    }
  __syncthreads();

  // out[e, c] = sum_b OB[e, b] * W_cb[c, b]
  // NOTE: 64*NCLS = 320 > 256 threads -> strided loop (round-1 bugfix: the
  // `if (tid < 320)` form left rows 51..63 of every tile unwritten).
  for (int t = tid; t < 64 * NCLS; t += 256) {
    int r = t / NCLS, c = t % NCLS;
    long erow = e0 + r;
    if (erow < EDG) {
      float o = OB[r][0] * W_cb[c * NBAS + 0] + OB[r][1] * W_cb[c * NBAS + 1];
      out[erow * NCLS + c] = o;
    }
  }
}

extern "C" void kernel_launch(void* const* d_in, const int* in_sizes, int n_in,
                              void* d_out, int out_size, void* d_ws,
                              size_t ws_size, hipStream_t stream) {
  const float* h_src  = (const float*)d_in[0];
  const float* h_dst  = (const float*)d_in[1];
  const float* efeats = (const float*)d_in[2];
  const int*   u_idx  = (const int*)d_in[3];
  const int*   v_idx  = (const int*)d_in[4];
  const float* W1     = (const float*)d_in[5];
  const float* b1     = (const float*)d_in[6];
  const float* W2     = (const float*)d_in[7];
  const float* b2     = (const float*)d_in[8];
  const float* W3     = (const float*)d_in[9];
  const float* b3     = (const float*)d_in[10];
  const float* W_comb = (const float*)d_in[11];
  const float* P      = (const float*)d_in[12];
  const float* W_cb   = (const float*)d_in[13];
  ushort* ws = (ushort*)d_ws;
  float* out = (float*)d_out;

  prep_kernel<<<(PREP_TOT + 255) / 256, 256, 0, stream>>>(W1, W2, W3, W_comb, P, ws);
  node_kernel<<<2 * ((NNODE + 63) / 64), 256, 0, stream>>>(h_src, h_dst, ws);
  edge_kernel<<<(EDG + 63) / 64, 256, 0, stream>>>(efeats, u_idx, v_idx,
                                                   b1, b2, b3, W_cb, ws, out);
}

// Round 3
// 503.660 us; speedup vs baseline: 1.0163x; 1.0163x over previous
//
#include <hip/hip_runtime.h>

#define NNODE 100000
#define EDG   500000
#define DD    128
#define FF    64
#define NCLS  5

// ws layout (ushort units). Weights stored bf16 ROW-MAJOR (A-operand of
// transposed GEMMs: D^T[m=outfeat][n=edge] = W[m][k] * ACT[n][k]).
#define OFF_W1   0                       // [128][64]
#define OFF_W2   8192                    // [128][128]
#define OFF_W3   24576
#define OFF_WCR  40960
#define OFF_WCL  57344
#define OFF_P0   73728
#define OFF_P1   90112
#define OFF_HU   106496                  // [NNODE][128] bf16
#define OFF_HV   (106496 + NNODE * DD)
#define PREP_TOT 106496

typedef __attribute__((ext_vector_type(8))) short short8;
typedef __attribute__((ext_vector_type(4))) float f32x4;

union U4 { uint4 v; ushort s[8]; };

__device__ __forceinline__ float bf2f(ushort u) {
  return __uint_as_float(((unsigned int)u) << 16);
}
__device__ __forceinline__ ushort f2bf(float f) {
  unsigned int u = __float_as_uint(f);
  u += 0x7FFF + ((u >> 16) & 1);   // round-to-nearest-even
  return (ushort)(u >> 16);
}

__device__ __forceinline__ void zacc(f32x4 a[2][4]) {
#pragma unroll
  for (int i = 0; i < 2; ++i)
#pragma unroll
    for (int j = 0; j < 4; ++j)
      a[i][j] = (f32x4){0.f, 0.f, 0.f, 0.f};
}

// Transposed GEMM: wave owns feats [m0,m0+32) x edges [n0,n0+64).
// A-frag: weights from global (row-major, 16B/lane, L2-hot).
// B-frag: activations from LDS (ds_read_b128).
__device__ __forceinline__ void gemm_T(const ushort (*act)[136],
                                       const ushort* __restrict__ W, int K,
                                       int ksteps, f32x4 acc[2][4],
                                       int m0, int n0, int l15, int q) {
  for (int ks = 0; ks < ksteps; ++ks) {
    const int ko = ks * 32 + q * 8;
    short8 a0 = *(const short8*)(W + (m0 + l15) * K + ko);
    short8 a1 = *(const short8*)(W + (m0 + 16 + l15) * K + ko);
#pragma unroll
    for (int nt = 0; nt < 4; ++nt) {
      short8 b = *(const short8*)&act[n0 + nt * 16 + l15][ko];
      acc[0][nt] = __builtin_amdgcn_mfma_f32_16x16x32_bf16(a0, b, acc[0][nt], 0, 0, 0);
      acc[1][nt] = __builtin_amdgcn_mfma_f32_16x16x32_bf16(a1, b, acc[1][nt], 0, 0, 0);
    }
  }
}

// D^T C-layout: lane holds edge = n0+nt*16+(lane&15), 4 contiguous feats
// m0+mt*16+q*4+r  ->  one ds_write_b64 per tile.
__device__ __forceinline__ void store_T(ushort (*dst)[136], f32x4 acc[2][4],
                                        const float* __restrict__ bias, int relu,
                                        int m0, int n0, int l15, int q) {
#pragma unroll
  for (int mt = 0; mt < 2; ++mt) {
    const int feat = m0 + mt * 16 + q * 4;
    float4 bv = bias ? *(const float4*)(bias + feat) : make_float4(0.f, 0.f, 0.f, 0.f);
#pragma unroll
    for (int nt = 0; nt < 4; ++nt) {
      const int edge = n0 + nt * 16 + l15;
      float v0 = acc[mt][nt][0] + bv.x, v1 = acc[mt][nt][1] + bv.y;
      float v2 = acc[mt][nt][2] + bv.z, v3 = acc[mt][nt][3] + bv.w;
      if (relu) {
        v0 = fmaxf(v0, 0.f); v1 = fmaxf(v1, 0.f);
        v2 = fmaxf(v2, 0.f); v3 = fmaxf(v3, 0.f);
      }
      ushort4 o; o.x = f2bf(v0); o.y = f2bf(v1); o.z = f2bf(v2); o.w = f2bf(v3);
      *(ushort4*)&dst[edge][feat] = o;
    }
  }
}

// ---------------- prep: bf16 row-major weight copies ----------------------
__global__ void __launch_bounds__(256) prep_kernel(
    const float* __restrict__ W1, const float* __restrict__ W2,
    const float* __restrict__ W3, const float* __restrict__ W_comb,
    const float* __restrict__ P, ushort* __restrict__ ws) {
  int idx = blockIdx.x * 256 + threadIdx.x;
  if (idx >= PREP_TOT) return;
  float val;
  if (idx < 8192) {
    val = W1[idx];
  } else {
    int r = idx - 8192, m = r >> 14, rr = r & 16383;
    switch (m) {
      case 0:  val = W2[rr]; break;
      case 1:  val = W3[rr]; break;
      case 2:  { int n = rr >> 7, k = rr & 127; val = W_comb[n * 256 + 128 + k]; } break;
      case 3:  { int n = rr >> 7, k = rr & 127; val = W_comb[n * 256 + k]; } break;
      case 4:  val = P[rr]; break;
      default: val = P[16384 + rr]; break;
    }
  }
  ws[idx] = f2bf(val);
}

// ---------------- node kernel: hu/hv = h @ Wcl^T, coalesced bf16 out ------
__global__ void __launch_bounds__(512, 4) node_kernel(
    const float* __restrict__ h_src, const float* __restrict__ h_dst,
    ushort* __restrict__ ws) {
  __shared__ ushort ACT[128][136];
  const int NT = (NNODE + 127) / 128;
  const int tid = threadIdx.x;
  const int w = tid >> 6, lane = tid & 63, l15 = lane & 15, q = lane >> 4;
  const int m0 = (w & 3) * 32, n0 = (w >> 2) * 64;
  const int bb = blockIdx.x;
  const float* h = (bb < NT) ? h_src : h_dst;
  ushort* op = ws + ((bb < NT) ? OFF_HU : OFF_HV);
  const int r0 = ((bb < NT) ? bb : bb - NT) * 128;
  const int srow = tid >> 2, part = tid & 3;
  int row = r0 + srow; if (row >= NNODE) row = NNODE - 1;
  {
    const float4* src = (const float4*)(h + (long)row * DD) + part * 8;
    ushort* d = &ACT[srow][part * 32];
#pragma unroll
    for (int i = 0; i < 8; ++i) {
      float4 v = src[i];
      ushort4 hh; hh.x = f2bf(v.x); hh.y = f2bf(v.y); hh.z = f2bf(v.z); hh.w = f2bf(v.w);
      *(ushort4*)(d + i * 4) = hh;
    }
  }
  __syncthreads();
  f32x4 acc[2][4];
  zacc(acc);
  gemm_T(ACT, ws + OFF_WCL, 128, 4, acc, m0, n0, l15, q);
  __syncthreads();
  store_T(ACT, acc, nullptr, 0, m0, n0, l15, q);
  __syncthreads();
  if (r0 + srow < NNODE) {
    const uint4* s = (const uint4*)&ACT[srow][part * 32];
    uint4* d = (uint4*)(op + (long)(r0 + srow) * DD + part * 32);
#pragma unroll
    for (int i = 0; i < 4; ++i) d[i] = s[i];
  }
}

// ---------------- fused edge kernel: 128 edges / 8 waves ------------------
__global__ void __launch_bounds__(512, 4) edge_kernel(
    const float* __restrict__ efeats, const int* __restrict__ u_idx,
    const int* __restrict__ v_idx, const float* __restrict__ b1,
    const float* __restrict__ b2, const float* __restrict__ b3,
    const float* __restrict__ W_cb, const ushort* __restrict__ ws,
    float* __restrict__ out) {
  __shared__ ushort ACT[128][136];
  __shared__ ushort EC[128][136];
  __shared__ float OB[128][2];

  const int tid = threadIdx.x;
  const int w = tid >> 6, lane = tid & 63;
  const int l15 = lane & 15, q = lane >> 4;
  const int m0 = (w & 3) * 32, n0 = (w >> 2) * 64;
  const long e0 = (long)blockIdx.x * 128;

  const int srow = tid >> 2, part = tid & 3;
  long grow = e0 + srow; if (grow >= EDG) grow = EDG - 1;
  const int vi = v_idx[grow], ui = u_idx[grow];

  // stage X = bf16(efeats tile) [128][64]
  {
    const float4* src = (const float4*)(efeats + grow * FF) + part * 4;
    ushort* d = &ACT[srow][part * 16];
#pragma unroll
    for (int i = 0; i < 4; ++i) {
      float4 v = src[i];
      ushort4 hh; hh.x = f2bf(v.x); hh.y = f2bf(v.y); hh.z = f2bf(v.z); hh.w = f2bf(v.w);
      *(ushort4*)(d + i * 4) = hh;
    }
  }
  __syncthreads();

  f32x4 acc[2][4];
  // e1 = relu(X @ W1^T + b1), K=64
  zacc(acc); gemm_T(ACT, ws + OFF_W1, 64, 2, acc, m0, n0, l15, q);
  __syncthreads(); store_T(ACT, acc, b1, 1, m0, n0, l15, q); __syncthreads();
  // e2 = relu(e1 @ W2^T + b2)
  zacc(acc); gemm_T(ACT, ws + OFF_W2, 128, 4, acc, m0, n0, l15, q);
  __syncthreads(); store_T(ACT, acc, b2, 1, m0, n0, l15, q); __syncthreads();
  // e3 = e2 @ W3^T + b3
  zacc(acc); gemm_T(ACT, ws + OFF_W3, 128, 4, acc, m0, n0, l15, q);
  __syncthreads(); store_T(ACT, acc, b3, 0, m0, n0, l15, q); __syncthreads();

  // prefetch hv row into regs; its latency hides behind the ec GEMM
  uint4 hvp[4];
  {
    const uint4* hp = (const uint4*)(ws + OFF_HV + (long)vi * DD + part * 32);
#pragma unroll
    for (int c = 0; c < 4; ++c) hvp[c] = hp[c];
  }
  // ec = e3 @ Wcr^T -> EC
  zacc(acc); gemm_T(ACT, ws + OFF_WCR, 128, 4, acc, m0, n0, l15, q);
  __syncthreads(); store_T(EC, acc, nullptr, 0, m0, n0, l15, q); __syncthreads();

  // V = hv[v_idx] + ec -> ACT ; zero OB
  {
#pragma unroll
    for (int c = 0; c < 4; ++c) {
      U4 a; a.v = hvp[c];
      U4 e; e.v = *(const uint4*)&EC[srow][part * 32 + c * 8];
      U4 o;
#pragma unroll
      for (int j = 0; j < 8; ++j) o.s[j] = f2bf(bf2f(a.s[j]) + bf2f(e.s[j]));
      *(uint4*)&ACT[srow][part * 32 + c * 8] = o.v;
    }
    if (tid < 256) OB[tid >> 1][tid & 1] = 0.f;
  }
  __syncthreads();

  // prefetch hu; latency hides behind the two P GEMMs
  uint4 hup[4];
  {
    const uint4* hp = (const uint4*)(ws + OFF_HU + (long)ui * DD + part * 32);
#pragma unroll
    for (int c = 0; c < 4; ++c) hup[c] = hp[c];
  }

  // T_b = V @ P_b^T (fused over bases to share B-frags)
  f32x4 tacc[2][2][4];
  zacc(tacc[0]); zacc(tacc[1]);
  for (int ks = 0; ks < 4; ++ks) {
    const int ko = ks * 32 + q * 8;
    short8 a00 = *(const short8*)(ws + OFF_P0 + (m0 + l15) * 128 + ko);
    short8 a01 = *(const short8*)(ws + OFF_P0 + (m0 + 16 + l15) * 128 + ko);
    short8 a10 = *(const short8*)(ws + OFF_P1 + (m0 + l15) * 128 + ko);
    short8 a11 = *(const short8*)(ws + OFF_P1 + (m0 + 16 + l15) * 128 + ko);
#pragma unroll
    for (int nt = 0; nt < 4; ++nt) {
      short8 b = *(const short8*)&ACT[n0 + nt * 16 + l15][ko];
      tacc[0][0][nt] = __builtin_amdgcn_mfma_f32_16x16x32_bf16(a00, b, tacc[0][0][nt], 0, 0, 0);
      tacc[0][1][nt] = __builtin_amdgcn_mfma_f32_16x16x32_bf16(a01, b, tacc[0][1][nt], 0, 0, 0);
      tacc[1][0][nt] = __builtin_amdgcn_mfma_f32_16x16x32_bf16(a10, b, tacc[1][0][nt], 0, 0, 0);
      tacc[1][1][nt] = __builtin_amdgcn_mfma_f32_16x16x32_bf16(a11, b, tacc[1][1][nt], 0, 0, 0);
    }
  }
  __syncthreads();

  // U = hu[u_idx] + ec -> ACT
  {
#pragma unroll
    for (int c = 0; c < 4; ++c) {
      U4 a; a.v = hup[c];
      U4 e; e.v = *(const uint4*)&EC[srow][part * 32 + c * 8];
      U4 o;
#pragma unroll
      for (int j = 0; j < 8; ++j) o.s[j] = f2bf(bf2f(a.s[j]) + bf2f(e.s[j]));
      *(uint4*)&ACT[srow][part * 32 + c * 8] = o.v;
    }
  }
  __syncthreads();

  // out_b[edge] = sum_feat U[edge][feat] * T_b[edge][feat]
#pragma unroll
  for (int nt = 0; nt < 4; ++nt) {
    const int edge = n0 + nt * 16 + l15;
    float pb0 = 0.f, pb1 = 0.f;
#pragma unroll
    for (int mt = 0; mt < 2; ++mt) {
      ushort4 u4 = *(const ushort4*)&ACT[edge][m0 + mt * 16 + q * 4];
      float uf;
      uf = bf2f(u4.x); pb0 += tacc[0][mt][nt][0] * uf; pb1 += tacc[1][mt][nt][0] * uf;
      uf = bf2f(u4.y); pb0 += tacc[0][mt][nt][1] * uf; pb1 += tacc[1][mt][nt][1] * uf;
      uf = bf2f(u4.z); pb0 += tacc[0][mt][nt][2] * uf; pb1 += tacc[1][mt][nt][2] * uf;
      uf = bf2f(u4.w); pb0 += tacc[0][mt][nt][3] * uf; pb1 += tacc[1][mt][nt][3] * uf;
    }
    pb0 += __shfl_xor(pb0, 16, 64); pb0 += __shfl_xor(pb0, 32, 64);
    pb1 += __shfl_xor(pb1, 16, 64); pb1 += __shfl_xor(pb1, 32, 64);
    if (q == 0) {
      atomicAdd(&OB[edge][0], pb0);
      atomicAdd(&OB[edge][1], pb1);
    }
  }
  __syncthreads();

  // out[e, c] = sum_b OB[e, b] * W_cb[c, b]
  for (int t = tid; t < 128 * NCLS; t += 512) {
    int r = t / NCLS, c = t % NCLS;
    long erow = e0 + r;
    if (erow < EDG) {
      out[erow * NCLS + c] = OB[r][0] * W_cb[c * 2] + OB[r][1] * W_cb[c * 2 + 1];
    }
  }
}

extern "C" void kernel_launch(void* const* d_in, const int* in_sizes, int n_in,
                              void* d_out, int out_size, void* d_ws,
                              size_t ws_size, hipStream_t stream) {
  const float* h_src  = (const float*)d_in[0];
  const float* h_dst  = (const float*)d_in[1];
  const float* efeats = (const float*)d_in[2];
  const int*   u_idx  = (const int*)d_in[3];
  const int*   v_idx  = (const int*)d_in[4];
  const float* W1     = (const float*)d_in[5];
  const float* b1     = (const float*)d_in[6];
  const float* W2     = (const float*)d_in[7];
  const float* b2     = (const float*)d_in[8];
  const float* W3     = (const float*)d_in[9];
  const float* b3     = (const float*)d_in[10];
  const float* W_comb = (const float*)d_in[11];
  const float* P      = (const float*)d_in[12];
  const float* W_cb   = (const float*)d_in[13];
  ushort* ws = (ushort*)d_ws;
  float* out = (float*)d_out;

  prep_kernel<<<(PREP_TOT + 255) / 256, 256, 0, stream>>>(W1, W2, W3, W_comb, P, ws);
  node_kernel<<<2 * ((NNODE + 127) / 128), 512, 0, stream>>>(h_src, h_dst, ws);
  edge_kernel<<<(EDG + 127) / 128, 512, 0, stream>>>(efeats, u_idx, v_idx,
                                                     b1, b2, b3, W_cb, ws, out);
}

// Round 4
// 500.628 us; speedup vs baseline: 1.0225x; 1.0061x over previous
//
#include <hip/hip_runtime.h>
#include <hip/hip_bf16.h>

#define NNODE 100000
#define EDG   500000
#define DD    128
#define FF    64
#define NCLS  5

// ws layout (ushort units). Weights bf16 ROW-MAJOR (A-operand of transposed
// GEMMs: D^T[m=outfeat][n=edge] = W[m][k] * ACT[n][k]).
#define OFF_W1   0                       // [128][64]
#define OFF_W2   8192                    // [128][128]
#define OFF_W3   24576
#define OFF_WCR  40960
#define OFF_WCL  57344
#define OFF_P0   73728
#define OFF_P1   90112
#define OFF_HU   106496                  // [NNODE][128] bf16
#define OFF_HV   (106496 + NNODE * DD)
#define PREP_TOT 106496

typedef __attribute__((ext_vector_type(8))) short short8;
typedef __attribute__((ext_vector_type(4))) float f32x4;

union U4 { uint4 v; ushort s[8]; };

__device__ __forceinline__ float bf2f(ushort u) {
  return __uint_as_float(((unsigned int)u) << 16);
}
__device__ __forceinline__ ushort f2bf(float f) {
  unsigned int u = __float_as_uint(f);
  u += 0x7FFF + ((u >> 16) & 1);
  return (ushort)(u >> 16);
}
// HW pack: v_cvt_pk_bf16_f32 (RNE) via hip_bf16 API
__device__ __forceinline__ ushort2 pk2(float a, float b) {
  __hip_bfloat162 t = __float22bfloat162_rn(make_float2(a, b));
  return *(ushort2*)&t;
}
__device__ __forceinline__ ushort4 pk4(float a, float b, float c, float d) {
  ushort2 lo = pk2(a, b), hi = pk2(c, d);
  ushort4 o; o.x = lo.x; o.y = lo.y; o.z = hi.x; o.w = hi.y; return o;
}

// XOR-swizzled LDS addressing: buffer rows are 128 ushorts (256 B, 64 dwords);
// granule (16 B) index is XORed with row&7 -> 16-row strided b128 access
// touches all 32 banks (2-way max = free). col%4==0 required.
__device__ __forceinline__ int sw(int row, int col) {
  return row * 128 + ((((col >> 3) ^ (row & 7)) << 3) | (col & 7));
}

__device__ __forceinline__ void zacc(f32x4 a[2][4]) {
#pragma unroll
  for (int i = 0; i < 2; ++i)
#pragma unroll
    for (int j = 0; j < 4; ++j)
      a[i][j] = (f32x4){0.f, 0.f, 0.f, 0.f};
}

// Transposed GEMM: wave owns feats [m0,m0+32) x edges [n0,n0+64).
// A: weights from global (row-major, 16B/lane, L2-hot). B: acts from LDS.
__device__ __forceinline__ void gemm_T(const ushort* act,
                                       const ushort* __restrict__ W, int K,
                                       int ksteps, f32x4 acc[2][4],
                                       int m0, int n0, int l15, int q) {
  for (int ks = 0; ks < ksteps; ++ks) {
    const int ko = ks * 32 + q * 8;
    short8 a0 = *(const short8*)(W + (m0 + l15) * K + ko);
    short8 a1 = *(const short8*)(W + (m0 + 16 + l15) * K + ko);
#pragma unroll
    for (int nt = 0; nt < 4; ++nt) {
      short8 b = *(const short8*)&act[sw(n0 + nt * 16 + l15, ko)];
      acc[0][nt] = __builtin_amdgcn_mfma_f32_16x16x32_bf16(a0, b, acc[0][nt], 0, 0, 0);
      acc[1][nt] = __builtin_amdgcn_mfma_f32_16x16x32_bf16(a1, b, acc[1][nt], 0, 0, 0);
    }
  }
}

// D^T C-layout: lane = edge n0+nt*16+l15, 4 contiguous feats m0+mt*16+q*4+r.
__device__ __forceinline__ void store_T(ushort* dst, f32x4 acc[2][4],
                                        const float* __restrict__ bias, int relu,
                                        int m0, int n0, int l15, int q) {
#pragma unroll
  for (int mt = 0; mt < 2; ++mt) {
    const int feat = m0 + mt * 16 + q * 4;
    float4 bv = bias ? *(const float4*)(bias + feat) : make_float4(0.f, 0.f, 0.f, 0.f);
#pragma unroll
    for (int nt = 0; nt < 4; ++nt) {
      const int edge = n0 + nt * 16 + l15;
      float v0 = acc[mt][nt][0] + bv.x, v1 = acc[mt][nt][1] + bv.y;
      float v2 = acc[mt][nt][2] + bv.z, v3 = acc[mt][nt][3] + bv.w;
      if (relu) {
        v0 = fmaxf(v0, 0.f); v1 = fmaxf(v1, 0.f);
        v2 = fmaxf(v2, 0.f); v3 = fmaxf(v3, 0.f);
      }
      *(ushort4*)&dst[sw(edge, feat)] = pk4(v0, v1, v2, v3);
    }
  }
}

// ---------------- prep: bf16 row-major weight copies ----------------------
__global__ void __launch_bounds__(256) prep_kernel(
    const float* __restrict__ W1, const float* __restrict__ W2,
    const float* __restrict__ W3, const float* __restrict__ W_comb,
    const float* __restrict__ P, ushort* __restrict__ ws) {
  int idx = blockIdx.x * 256 + threadIdx.x;
  if (idx >= PREP_TOT) return;
  float val;
  if (idx < 8192) {
    val = W1[idx];
  } else {
    int r = idx - 8192, m = r >> 14, rr = r & 16383;
    switch (m) {
      case 0:  val = W2[rr]; break;
      case 1:  val = W3[rr]; break;
      case 2:  { int n = rr >> 7, k = rr & 127; val = W_comb[n * 256 + 128 + k]; } break;
      case 3:  { int n = rr >> 7, k = rr & 127; val = W_comb[n * 256 + k]; } break;
      case 4:  val = P[rr]; break;
      default: val = P[16384 + rr]; break;
    }
  }
  ws[idx] = f2bf(val);
}

// ---------------- node kernel: hu/hv = h @ Wcl^T ---------------------------
__global__ void __launch_bounds__(512, 4) node_kernel(
    const float* __restrict__ h_src, const float* __restrict__ h_dst,
    ushort* __restrict__ ws) {
  __shared__ ushort BUF[2][128][128];
  ushort* A = &BUF[0][0][0];
  ushort* B = &BUF[1][0][0];
  const int NT = (NNODE + 127) / 128;
  const int tid = threadIdx.x;
  const int w = tid >> 6, lane = tid & 63, l15 = lane & 15, q = lane >> 4;
  const int m0 = (w & 3) * 32, n0 = (w >> 2) * 64;
  const int bb = blockIdx.x;
  const float* h = (bb < NT) ? h_src : h_dst;
  ushort* op = ws + ((bb < NT) ? OFF_HU : OFF_HV);
  const int r0 = ((bb < NT) ? bb : bb - NT) * 128;
  const int srow = tid >> 2, part = tid & 3;
  int row = r0 + srow; if (row >= NNODE) row = NNODE - 1;
  {
    const float4* src = (const float4*)(h + (long)row * DD) + part * 8;
#pragma unroll
    for (int i = 0; i < 8; ++i) {
      float4 v = src[i];
      *(ushort4*)&A[sw(srow, part * 32 + i * 4)] = pk4(v.x, v.y, v.z, v.w);
    }
  }
  __syncthreads();
  f32x4 acc[2][4];
  zacc(acc);
  gemm_T(A, ws + OFF_WCL, 128, 4, acc, m0, n0, l15, q);
  store_T(B, acc, nullptr, 0, m0, n0, l15, q);
  __syncthreads();
  if (r0 + srow < NNODE) {
    uint4* d = (uint4*)(op + (long)(r0 + srow) * DD + part * 32);
#pragma unroll
    for (int i = 0; i < 4; ++i)
      d[i] = *(const uint4*)&B[sw(srow, part * 32 + i * 8)];
  }
}

// ---------------- fused edge kernel: 128 edges / 8 waves -------------------
__global__ void __launch_bounds__(512, 4) edge_kernel(
    const float* __restrict__ efeats, const int* __restrict__ u_idx,
    const int* __restrict__ v_idx, const float* __restrict__ b1,
    const float* __restrict__ b2, const float* __restrict__ b3,
    const float* __restrict__ W_cb, const ushort* __restrict__ ws,
    float* __restrict__ out) {
  __shared__ ushort BUF[2][128][128];   // ping-pong activation buffers
  __shared__ float OB[128][2];
  ushort* A = &BUF[0][0][0];
  ushort* B = &BUF[1][0][0];

  const int tid = threadIdx.x;
  const int w = tid >> 6, lane = tid & 63;
  const int l15 = lane & 15, q = lane >> 4;
  const int m0 = (w & 3) * 32, n0 = (w >> 2) * 64;
  const long e0 = (long)blockIdx.x * 128;

  const int srow = tid >> 2, part = tid & 3;
  long grow = e0 + srow; if (grow >= EDG) grow = EDG - 1;
  const int vi = v_idx[grow], ui = u_idx[grow];

  // stage X -> A   [128 edges][64 feats]
  {
    const float4* src = (const float4*)(efeats + grow * FF) + part * 4;
#pragma unroll
    for (int i = 0; i < 4; ++i) {
      float4 v = src[i];
      *(ushort4*)&A[sw(srow, part * 16 + i * 4)] = pk4(v.x, v.y, v.z, v.w);
    }
  }
  __syncthreads();                                    // 1

  f32x4 acc[2][4];
  // e1 = relu(X@W1^T+b1): A -> B
  zacc(acc); gemm_T(A, ws + OFF_W1, 64, 2, acc, m0, n0, l15, q);
  store_T(B, acc, b1, 1, m0, n0, l15, q);
  __syncthreads();                                    // 2
  // e2: B -> A
  zacc(acc); gemm_T(B, ws + OFF_W2, 128, 4, acc, m0, n0, l15, q);
  store_T(A, acc, b2, 1, m0, n0, l15, q);
  __syncthreads();                                    // 3
  // e3: A -> B
  zacc(acc); gemm_T(A, ws + OFF_W3, 128, 4, acc, m0, n0, l15, q);
  store_T(B, acc, b3, 0, m0, n0, l15, q);
  __syncthreads();                                    // 4

  // hv prefetch (covered by ec GEMM)
  uint4 hvp[4];
  {
    const uint4* hp = (const uint4*)(ws + OFF_HV + (long)vi * DD + part * 32);
#pragma unroll
    for (int c = 0; c < 4; ++c) hvp[c] = hp[c];
  }
  // ec = e3@Wcr^T: B -> A   (A = ec, live until U-build)
  zacc(acc); gemm_T(B, ws + OFF_WCR, 128, 4, acc, m0, n0, l15, q);
  store_T(A, acc, nullptr, 0, m0, n0, l15, q);
  __syncthreads();                                    // 5

  // V = hv + ec: A -> B ; zero OB
  {
#pragma unroll
    for (int c = 0; c < 4; ++c) {
      U4 a; a.v = hvp[c];
      U4 e; e.v = *(const uint4*)&A[sw(srow, part * 32 + c * 8)];
      U4 o;
#pragma unroll
      for (int j = 0; j < 8; j += 2) {
        ushort2 p = pk2(bf2f(a.s[j]) + bf2f(e.s[j]),
                        bf2f(a.s[j + 1]) + bf2f(e.s[j + 1]));
        o.s[j] = p.x; o.s[j + 1] = p.y;
      }
      *(uint4*)&B[sw(srow, part * 32 + c * 8)] = o.v;
    }
    if (tid < 256) OB[tid >> 1][tid & 1] = 0.f;
  }
  __syncthreads();                                    // 6

  // hu prefetch (covered by P GEMMs)
  uint4 hup[4];
  {
    const uint4* hp = (const uint4*)(ws + OFF_HU + (long)ui * DD + part * 32);
#pragma unroll
    for (int c = 0; c < 4; ++c) hup[c] = hp[c];
  }

  // T_b = V @ P_b^T (bases fused to share B-frags): read B
  f32x4 tacc[2][2][4];
  zacc(tacc[0]); zacc(tacc[1]);
  for (int ks = 0; ks < 4; ++ks) {
    const int ko = ks * 32 + q * 8;
    short8 a00 = *(const short8*)(ws + OFF_P0 + (m0 + l15) * 128 + ko);
    short8 a01 = *(const short8*)(ws + OFF_P0 + (m0 + 16 + l15) * 128 + ko);
    short8 a10 = *(const short8*)(ws + OFF_P1 + (m0 + l15) * 128 + ko);
    short8 a11 = *(const short8*)(ws + OFF_P1 + (m0 + 16 + l15) * 128 + ko);
#pragma unroll
    for (int nt = 0; nt < 4; ++nt) {
      short8 b = *(const short8*)&B[sw(n0 + nt * 16 + l15, ko)];
      tacc[0][0][nt] = __builtin_amdgcn_mfma_f32_16x16x32_bf16(a00, b, tacc[0][0][nt], 0, 0, 0);
      tacc[0][1][nt] = __builtin_amdgcn_mfma_f32_16x16x32_bf16(a01, b, tacc[0][1][nt], 0, 0, 0);
      tacc[1][0][nt] = __builtin_amdgcn_mfma_f32_16x16x32_bf16(a10, b, tacc[1][0][nt], 0, 0, 0);
      tacc[1][1][nt] = __builtin_amdgcn_mfma_f32_16x16x32_bf16(a11, b, tacc[1][1][nt], 0, 0, 0);
    }
  }
  __syncthreads();                                    // 7 (B reads done)

  // U = hu + ec: A -> B
  {
#pragma unroll
    for (int c = 0; c < 4; ++c) {
      U4 a; a.v = hup[c];
      U4 e; e.v = *(const uint4*)&A[sw(srow, part * 32 + c * 8)];
      U4 o;
#pragma unroll
      for (int j = 0; j < 8; j += 2) {
        ushort2 p = pk2(bf2f(a.s[j]) + bf2f(e.s[j]),
                        bf2f(a.s[j + 1]) + bf2f(e.s[j + 1]));
        o.s[j] = p.x; o.s[j + 1] = p.y;
      }
      *(uint4*)&B[sw(srow, part * 32 + c * 8)] = o.v;
    }
  }
  __syncthreads();                                    // 8

  // out_b[edge] = sum_feat U[edge][feat] * T_b[edge][feat]
#pragma unroll
  for (int nt = 0; nt < 4; ++nt) {
    const int edge = n0 + nt * 16 + l15;
    float pb0 = 0.f, pb1 = 0.f;
#pragma unroll
    for (int mt = 0; mt < 2; ++mt) {
      ushort4 u4 = *(const ushort4*)&B[sw(edge, m0 + mt * 16 + q * 4)];
      float uf;
      uf = bf2f(u4.x); pb0 += tacc[0][mt][nt][0] * uf; pb1 += tacc[1][mt][nt][0] * uf;
      uf = bf2f(u4.y); pb0 += tacc[0][mt][nt][1] * uf; pb1 += tacc[1][mt][nt][1] * uf;
      uf = bf2f(u4.z); pb0 += tacc[0][mt][nt][2] * uf; pb1 += tacc[1][mt][nt][2] * uf;
      uf = bf2f(u4.w); pb0 += tacc[0][mt][nt][3] * uf; pb1 += tacc[1][mt][nt][3] * uf;
    }
    pb0 += __shfl_xor(pb0, 16, 64); pb0 += __shfl_xor(pb0, 32, 64);
    pb1 += __shfl_xor(pb1, 16, 64); pb1 += __shfl_xor(pb1, 32, 64);
    if (q == 0) {
      atomicAdd(&OB[edge][0], pb0);
      atomicAdd(&OB[edge][1], pb1);
    }
  }
  __syncthreads();                                    // 9

  for (int t = tid; t < 128 * NCLS; t += 512) {
    int r = t / NCLS, c = t % NCLS;
    long erow = e0 + r;
    if (erow < EDG) {
      out[erow * NCLS + c] = OB[r][0] * W_cb[c * 2] + OB[r][1] * W_cb[c * 2 + 1];
    }
  }
}

extern "C" void kernel_launch(void* const* d_in, const int* in_sizes, int n_in,
                              void* d_out, int out_size, void* d_ws,
                              size_t ws_size, hipStream_t stream) {
  const float* h_src  = (const float*)d_in[0];
  const float* h_dst  = (const float*)d_in[1];
  const float* efeats = (const float*)d_in[2];
  const int*   u_idx  = (const int*)d_in[3];
  const int*   v_idx  = (const int*)d_in[4];
  const float* W1     = (const float*)d_in[5];
  const float* b1     = (const float*)d_in[6];
  const float* W2     = (const float*)d_in[7];
  const float* b2     = (const float*)d_in[8];
  const float* W3     = (const float*)d_in[9];
  const float* b3     = (const float*)d_in[10];
  const float* W_comb = (const float*)d_in[11];
  const float* P      = (const float*)d_in[12];
  const float* W_cb   = (const float*)d_in[13];
  ushort* ws = (ushort*)d_ws;
  float* out = (float*)d_out;

  prep_kernel<<<(PREP_TOT + 255) / 256, 256, 0, stream>>>(W1, W2, W3, W_comb, P, ws);
  node_kernel<<<2 * ((NNODE + 127) / 128), 512, 0, stream>>>(h_src, h_dst, ws);
  edge_kernel<<<(EDG + 127) / 128, 512, 0, stream>>>(efeats, u_idx, v_idx,
                                                     b1, b2, b3, W_cb, ws, out);
}

// Round 5
// 462.519 us; speedup vs baseline: 1.1067x; 1.0824x over previous
//
#include <hip/hip_runtime.h>
#include <hip/hip_bf16.h>

#define NNODE 100000
#define EDG   500000
#define DD    128
#define FF    64
#define NCLS  5

// ws layout (ushort units). Weights bf16 ROW-MAJOR (A-operand of transposed
// GEMMs: D^T[m=outfeat][n=edge] = W[m][k] * ACT[n][k]).
#define OFF_W1   0                       // [128][64]
#define OFF_W2   8192                    // [128][128]
#define OFF_W3   24576
#define OFF_WCR  40960
#define OFF_WCL  57344
#define OFF_P0   73728
#define OFF_P1   90112
#define OFF_HU   106496                  // [NNODE][128] bf16
#define OFF_HV   (106496 + NNODE * DD)
#define PREP_TOT 106496

typedef __attribute__((ext_vector_type(8))) short short8;
typedef __attribute__((ext_vector_type(4))) float f32x4;

union U4 { uint4 v; ushort s[8]; };

__device__ __forceinline__ float bf2f(ushort u) {
  return __uint_as_float(((unsigned int)u) << 16);
}
__device__ __forceinline__ ushort f2bf(float f) {
  unsigned int u = __float_as_uint(f);
  u += 0x7FFF + ((u >> 16) & 1);
  return (ushort)(u >> 16);
}
__device__ __forceinline__ ushort2 pk2(float a, float b) {
  __hip_bfloat162 t = __float22bfloat162_rn(make_float2(a, b));
  return *(ushort2*)&t;
}
__device__ __forceinline__ ushort4 pk4(float a, float b, float c, float d) {
  ushort2 lo = pk2(a, b), hi = pk2(c, d);
  ushort4 o; o.x = lo.x; o.y = lo.y; o.z = hi.x; o.w = hi.y; return o;
}

// XOR-swizzled LDS addressing (rows = 128 ushorts = 256 B; 16B granule index
// XORed with row&7). col%4==0 required.
__device__ __forceinline__ int sw(int row, int col) {
  return row * 128 + ((((col >> 3) ^ (row & 7)) << 3) | (col & 7));
}

__device__ __forceinline__ void zacc(f32x4 a[2][4]) {
#pragma unroll
  for (int i = 0; i < 2; ++i)
#pragma unroll
    for (int j = 0; j < 4; ++j)
      a[i][j] = (f32x4){0.f, 0.f, 0.f, 0.f};
}

// Transposed GEMM: wave owns feats [m0,m0+32) x all 64 edges.
// A: weights from global (row-major, L2-hot). B: acts from LDS.
__device__ __forceinline__ void gemm_T(const ushort* act,
                                       const ushort* __restrict__ W, int K,
                                       int ksteps, f32x4 acc[2][4],
                                       int m0, int l15, int q) {
  for (int ks = 0; ks < ksteps; ++ks) {
    const int ko = ks * 32 + q * 8;
    short8 a0 = *(const short8*)(W + (m0 + l15) * K + ko);
    short8 a1 = *(const short8*)(W + (m0 + 16 + l15) * K + ko);
#pragma unroll
    for (int nt = 0; nt < 4; ++nt) {
      short8 b = *(const short8*)&act[sw(nt * 16 + l15, ko)];
      acc[0][nt] = __builtin_amdgcn_mfma_f32_16x16x32_bf16(a0, b, acc[0][nt], 0, 0, 0);
      acc[1][nt] = __builtin_amdgcn_mfma_f32_16x16x32_bf16(a1, b, acc[1][nt], 0, 0, 0);
    }
  }
}

// D^T C-layout: lane = edge nt*16+l15, 4 contiguous feats m0+mt*16+q*4+r.
__device__ __forceinline__ void store_T(ushort* dst, f32x4 acc[2][4],
                                        const float* __restrict__ bias, int relu,
                                        int m0, int l15, int q) {
#pragma unroll
  for (int mt = 0; mt < 2; ++mt) {
    const int feat = m0 + mt * 16 + q * 4;
    float4 bv = bias ? *(const float4*)(bias + feat) : make_float4(0.f, 0.f, 0.f, 0.f);
#pragma unroll
    for (int nt = 0; nt < 4; ++nt) {
      const int edge = nt * 16 + l15;
      float v0 = acc[mt][nt][0] + bv.x, v1 = acc[mt][nt][1] + bv.y;
      float v2 = acc[mt][nt][2] + bv.z, v3 = acc[mt][nt][3] + bv.w;
      if (relu) {
        v0 = fmaxf(v0, 0.f); v1 = fmaxf(v1, 0.f);
        v2 = fmaxf(v2, 0.f); v3 = fmaxf(v3, 0.f);
      }
      *(ushort4*)&dst[sw(edge, feat)] = pk4(v0, v1, v2, v3);
    }
  }
}

// ---------------- prep: bf16 row-major weight copies ----------------------
__global__ void __launch_bounds__(256) prep_kernel(
    const float* __restrict__ W1, const float* __restrict__ W2,
    const float* __restrict__ W3, const float* __restrict__ W_comb,
    const float* __restrict__ P, ushort* __restrict__ ws) {
  int idx = blockIdx.x * 256 + threadIdx.x;
  if (idx >= PREP_TOT) return;
  float val;
  if (idx < 8192) {
    val = W1[idx];
  } else {
    int r = idx - 8192, m = r >> 14, rr = r & 16383;
    switch (m) {
      case 0:  val = W2[rr]; break;
      case 1:  val = W3[rr]; break;
      case 2:  { int n = rr >> 7, k = rr & 127; val = W_comb[n * 256 + 128 + k]; } break;
      case 3:  { int n = rr >> 7, k = rr & 127; val = W_comb[n * 256 + k]; } break;
      case 4:  val = P[rr]; break;
      default: val = P[16384 + rr]; break;
    }
  }
  ws[idx] = f2bf(val);
}

// ---------------- node kernel: hu/hv = h @ Wcl^T --------------------------
// 64 rows / 256 threads / ~33 KB LDS -> 4 blocks/CU.
__global__ void __launch_bounds__(256, 4) node_kernel(
    const float* __restrict__ h_src, const float* __restrict__ h_dst,
    ushort* __restrict__ ws) {
  __shared__ ushort BUF[2][64][128];
  ushort* A = &BUF[0][0][0];
  ushort* B = &BUF[1][0][0];
  const int NT = (NNODE + 63) / 64;
  const int tid = threadIdx.x;
  const int w = tid >> 6, lane = tid & 63, l15 = lane & 15, q = lane >> 4;
  const int m0 = w * 32;
  const int bb = blockIdx.x;
  const float* h = (bb < NT) ? h_src : h_dst;
  ushort* op = ws + ((bb < NT) ? OFF_HU : OFF_HV);
  const int r0 = ((bb < NT) ? bb : bb - NT) * 64;
  const int srow = tid >> 2, part = tid & 3;
  int row = r0 + srow; if (row >= NNODE) row = NNODE - 1;
  {
    const float4* src = (const float4*)(h + (long)row * DD) + part * 8;
#pragma unroll
    for (int c = 0; c < 4; ++c) {
      float4 v0 = src[c * 2], v1 = src[c * 2 + 1];
      U4 o;
      *(ushort4*)&o.s[0] = pk4(v0.x, v0.y, v0.z, v0.w);
      *(ushort4*)&o.s[4] = pk4(v1.x, v1.y, v1.z, v1.w);
      *(uint4*)&A[sw(srow, part * 32 + c * 8)] = o.v;
    }
  }
  __syncthreads();
  f32x4 acc[2][4];
  zacc(acc);
  gemm_T(A, ws + OFF_WCL, 128, 4, acc, m0, l15, q);
  store_T(B, acc, nullptr, 0, m0, l15, q);
  __syncthreads();
  if (r0 + srow < NNODE) {
    uint4* d = (uint4*)(op + (long)(r0 + srow) * DD + part * 32);
#pragma unroll
    for (int i = 0; i < 4; ++i)
      d[i] = *(const uint4*)&B[sw(srow, part * 32 + i * 8)];
  }
}

// ---------------- fused edge kernel: 64 edges / 4 waves -------------------
__global__ void __launch_bounds__(256, 4) edge_kernel(
    const float* __restrict__ efeats, const int* __restrict__ u_idx,
    const int* __restrict__ v_idx, const float* __restrict__ b1,
    const float* __restrict__ b2, const float* __restrict__ b3,
    const float* __restrict__ W_cb, const ushort* __restrict__ ws,
    float* __restrict__ out) {
  __shared__ ushort BUF[2][64][128];
  __shared__ float OB[64][2];
  ushort* A = &BUF[0][0][0];
  ushort* B = &BUF[1][0][0];

  const int tid = threadIdx.x;
  const int lane = tid & 63;
  const int l15 = lane & 15, q = lane >> 4;
  const int m0 = (tid >> 6) * 32;
  const long e0 = (long)blockIdx.x * 64;

  const int srow = tid >> 2, part = tid & 3;
  long grow = e0 + srow; if (grow >= EDG) grow = EDG - 1;
  const int vi = v_idx[grow], ui = u_idx[grow];

  // stage X -> A   [64 edges][64 feats]
  {
    const float4* src = (const float4*)(efeats + grow * FF) + part * 4;
#pragma unroll
    for (int c = 0; c < 2; ++c) {
      float4 v0 = src[c * 2], v1 = src[c * 2 + 1];
      U4 o;
      *(ushort4*)&o.s[0] = pk4(v0.x, v0.y, v0.z, v0.w);
      *(ushort4*)&o.s[4] = pk4(v1.x, v1.y, v1.z, v1.w);
      *(uint4*)&A[sw(srow, part * 16 + c * 8)] = o.v;
    }
  }
  __syncthreads();                                    // 1

  f32x4 acc[2][4];
  // e1 = relu(X@W1^T+b1): A -> B
  zacc(acc); gemm_T(A, ws + OFF_W1, 64, 2, acc, m0, l15, q);
  store_T(B, acc, b1, 1, m0, l15, q);
  __syncthreads();                                    // 2
  // e2: B -> A
  zacc(acc); gemm_T(B, ws + OFF_W2, 128, 4, acc, m0, l15, q);
  store_T(A, acc, b2, 1, m0, l15, q);
  __syncthreads();                                    // 3
  // e3: A -> B
  zacc(acc); gemm_T(A, ws + OFF_W3, 128, 4, acc, m0, l15, q);
  store_T(B, acc, b3, 0, m0, l15, q);
  __syncthreads();                                    // 4

  // hv prefetch (covered by ec GEMM)
  uint4 hvp[4];
  {
    const uint4* hp = (const uint4*)(ws + OFF_HV + (long)vi * DD + part * 32);
#pragma unroll
    for (int c = 0; c < 4; ++c) hvp[c] = hp[c];
  }
  // ec = e3@Wcr^T: B -> A   (A = ec, live until U-build)
  zacc(acc); gemm_T(B, ws + OFF_WCR, 128, 4, acc, m0, l15, q);
  store_T(A, acc, nullptr, 0, m0, l15, q);
  __syncthreads();                                    // 5

  // V = hv + ec: A -> B ; zero OB
  {
#pragma unroll
    for (int c = 0; c < 4; ++c) {
      U4 a; a.v = hvp[c];
      U4 e; e.v = *(const uint4*)&A[sw(srow, part * 32 + c * 8)];
      U4 o;
#pragma unroll
      for (int j = 0; j < 8; j += 2) {
        ushort2 p = pk2(bf2f(a.s[j]) + bf2f(e.s[j]),
                        bf2f(a.s[j + 1]) + bf2f(e.s[j + 1]));
        o.s[j] = p.x; o.s[j + 1] = p.y;
      }
      *(uint4*)&B[sw(srow, part * 32 + c * 8)] = o.v;
    }
    if (tid < 128) OB[tid >> 1][tid & 1] = 0.f;
  }
  __syncthreads();                                    // 6

  // hu prefetch (covered by P GEMMs)
  uint4 hup[4];
  {
    const uint4* hp = (const uint4*)(ws + OFF_HU + (long)ui * DD + part * 32);
#pragma unroll
    for (int c = 0; c < 4; ++c) hup[c] = hp[c];
  }

  // T_b = V @ P_b^T (bases fused to share B-frags): read B
  f32x4 tacc[2][2][4];
  zacc(tacc[0]); zacc(tacc[1]);
  for (int ks = 0; ks < 4; ++ks) {
    const int ko = ks * 32 + q * 8;
    short8 a00 = *(const short8*)(ws + OFF_P0 + (m0 + l15) * 128 + ko);
    short8 a01 = *(const short8*)(ws + OFF_P0 + (m0 + 16 + l15) * 128 + ko);
    short8 a10 = *(const short8*)(ws + OFF_P1 + (m0 + l15) * 128 + ko);
    short8 a11 = *(const short8*)(ws + OFF_P1 + (m0 + 16 + l15) * 128 + ko);
#pragma unroll
    for (int nt = 0; nt < 4; ++nt) {
      short8 b = *(const short8*)&B[sw(nt * 16 + l15, ko)];
      tacc[0][0][nt] = __builtin_amdgcn_mfma_f32_16x16x32_bf16(a00, b, tacc[0][0][nt], 0, 0, 0);
      tacc[0][1][nt] = __builtin_amdgcn_mfma_f32_16x16x32_bf16(a01, b, tacc[0][1][nt], 0, 0, 0);
      tacc[1][0][nt] = __builtin_amdgcn_mfma_f32_16x16x32_bf16(a10, b, tacc[1][0][nt], 0, 0, 0);
      tacc[1][1][nt] = __builtin_amdgcn_mfma_f32_16x16x32_bf16(a11, b, tacc[1][1][nt], 0, 0, 0);
    }
  }
  __syncthreads();                                    // 7 (B reads done)

  // U = hu + ec: A -> B
  {
#pragma unroll
    for (int c = 0; c < 4; ++c) {
      U4 a; a.v = hup[c];
      U4 e; e.v = *(const uint4*)&A[sw(srow, part * 32 + c * 8)];
      U4 o;
#pragma unroll
      for (int j = 0; j < 8; j += 2) {
        ushort2 p = pk2(bf2f(a.s[j]) + bf2f(e.s[j]),
                        bf2f(a.s[j + 1]) + bf2f(e.s[j + 1]));
        o.s[j] = p.x; o.s[j + 1] = p.y;
      }
      *(uint4*)&B[sw(srow, part * 32 + c * 8)] = o.v;
    }
  }
  __syncthreads();                                    // 8

  // out_b[edge] = sum_feat U[edge][feat] * T_b[edge][feat]
#pragma unroll
  for (int nt = 0; nt < 4; ++nt) {
    const int edge = nt * 16 + l15;
    float pb0 = 0.f, pb1 = 0.f;
#pragma unroll
    for (int mt = 0; mt < 2; ++mt) {
      ushort4 u4 = *(const ushort4*)&B[sw(edge, m0 + mt * 16 + q * 4)];
      float uf;
      uf = bf2f(u4.x); pb0 += tacc[0][mt][nt][0] * uf; pb1 += tacc[1][mt][nt][0] * uf;
      uf = bf2f(u4.y); pb0 += tacc[0][mt][nt][1] * uf; pb1 += tacc[1][mt][nt][1] * uf;
      uf = bf2f(u4.z); pb0 += tacc[0][mt][nt][2] * uf; pb1 += tacc[1][mt][nt][2] * uf;
      uf = bf2f(u4.w); pb0 += tacc[0][mt][nt][3] * uf; pb1 += tacc[1][mt][nt][3] * uf;
    }
    pb0 += __shfl_xor(pb0, 16, 64); pb0 += __shfl_xor(pb0, 32, 64);
    pb1 += __shfl_xor(pb1, 16, 64); pb1 += __shfl_xor(pb1, 32, 64);
    if (q == 0) {
      atomicAdd(&OB[edge][0], pb0);
      atomicAdd(&OB[edge][1], pb1);
    }
  }
  __syncthreads();                                    // 9

  for (int t = tid; t < 64 * NCLS; t += 256) {
    int r = t / NCLS, c = t % NCLS;
    long erow = e0 + r;
    if (erow < EDG) {
      out[erow * NCLS + c] = OB[r][0] * W_cb[c * 2] + OB[r][1] * W_cb[c * 2 + 1];
    }
  }
}

extern "C" void kernel_launch(void* const* d_in, const int* in_sizes, int n_in,
                              void* d_out, int out_size, void* d_ws,
                              size_t ws_size, hipStream_t stream) {
  const float* h_src  = (const float*)d_in[0];
  const float* h_dst  = (const float*)d_in[1];
  const float* efeats = (const float*)d_in[2];
  const int*   u_idx  = (const int*)d_in[3];
  const int*   v_idx  = (const int*)d_in[4];
  const float* W1     = (const float*)d_in[5];
  const float* b1     = (const float*)d_in[6];
  const float* W2     = (const float*)d_in[7];
  const float* b2     = (const float*)d_in[8];
  const float* W3     = (const float*)d_in[9];
  const float* b3     = (const float*)d_in[10];
  const float* W_comb = (const float*)d_in[11];
  const float* P      = (const float*)d_in[12];
  const float* W_cb   = (const float*)d_in[13];
  ushort* ws = (ushort*)d_ws;
  float* out = (float*)d_out;

  prep_kernel<<<(PREP_TOT + 255) / 256, 256, 0, stream>>>(W1, W2, W3, W_comb, P, ws);
  node_kernel<<<2 * ((NNODE + 63) / 64), 256, 0, stream>>>(h_src, h_dst, ws);
  edge_kernel<<<(EDG + 63) / 64, 256, 0, stream>>>(efeats, u_idx, v_idx,
                                                   b1, b2, b3, W_cb, ws, out);
}